// Round 1
// baseline (4292.491 us; speedup 1.0000x reference)
//
#include <hip/hip_runtime.h>
#include <cstdint>
#include <cstddef>

#define T_LEN 16384
#define BATCH 8
#define NLAYER 9

typedef _Float16 f16;
typedef __attribute__((ext_vector_type(8))) _Float16 f16x8;
typedef __attribute__((ext_vector_type(4))) float f32x4;
#define MFMA_F16 __builtin_amdgcn_mfma_f32_16x16x32_f16

__device__ __forceinline__ float fast_sigmoid(float x) {
    return 1.0f / (1.0f + __expf(-x));
}
__device__ __forceinline__ float fast_tanh(float x) {
    return 1.0f - 2.0f / (__expf(2.0f * x) + 1.0f);
}

// ---------------------------------------------------------------------------
// Weight prepack to fp16, B-fragment order [n][k32-chunk], LINEAR layout.
//  Both wA and wB are read DIRECT from L2 by the layer kernel (weights are
//  192+64 KB per layer, shared by all 2048 blocks -> L2-resident). No LDS
//  staging => no swizzle needed.
// ---------------------------------------------------------------------------
__global__ __launch_bounds__(256) void prep_weights(
    const float* __restrict__ cw, const float* __restrict__ ow,
    const float* __restrict__ o1w, f16* __restrict__ wA, f16* __restrict__ wB)
{
    int n = blockIdx.x * 256 + threadIdx.x;
    const int NA = NLAYER * 12 * 256 * 32;   // 884736
    const int NB = NLAYER * 4 * 256 * 32;    // 294912
    if (n < NA) {
        int kp = n & 31; int q = n >> 5;
        int c = q & 255; q >>= 8;
        int ch = q % 12; int l = q / 12;
        int tap = ch >> 2;
        int r = (ch & 3) * 32 + kp;
        wA[n] = (f16)cw[((size_t)(l * 256 + c) * 128 + r) * 3 + tap];
    } else if (n < NA + NB) {
        int m = n - NA;
        int kp = m & 31; int q = m >> 5;
        int c = q & 255; q >>= 8;
        int ch = q & 3; int l = q >> 2;
        int k = ch * 32 + kp;
        float v = (c < 128) ? ow[(size_t)(l * 128 + c) * 128 + k]
                            : o1w[(size_t)(c - 128) * 1152 + l * 128 + k];
        wB[m] = (f16)v;
    }
}

// h[b][t][r] = tanh(iw[r]*x[b][t] + ib[r]) (fp16);  acc1 zero-init (fp16)
__global__ __launch_bounds__(256) void input_init(
    const float* __restrict__ x, const float* __restrict__ iw,
    const float* __restrict__ ib,
    f16* __restrict__ h, f16* __restrict__ acc1)
{
    int n = blockIdx.x * 256 + threadIdx.x;
    int r = n & 127; int bt = n >> 7;
    h[n] = (f16)fast_tanh(iw[r] * x[bt] + ib[r]);
    acc1[n] = (f16)0.0f;
}

// ---------------------------------------------------------------------------
// One layer. Block 256 thr = 4 waves (mg = w&1 splits M, ng = w>>1 splits N).
// Block tile M=64 x N=256; wave tile M=32 x N=128 (gate-paired filters).
// Phase 1 AND phase 2 read B direct from L2 (weights are L2-resident; the
//   old global_load_lds staging paid a vmcnt(0) DMA drain at each of 12
//   barriers -> latency-bound at MfmaUtil 16%). Phase 1 is now barrier-free
//   straight-line code the compiler software-pipelines.
// LDS = zs only (17.4 KB) -> 9 blocks/CU cap; grid is 8/CU -> full residency
//   (32 waves/CU vs 20 before). launch_bounds(256,8) caps VGPR+AGPR at 256.
// ---------------------------------------------------------------------------
__global__ __launch_bounds__(256, 8) void layer_kernel(
    const f16* __restrict__ h_in, f16* __restrict__ h_out,
    f16* __restrict__ acc1,
    const f16* __restrict__ wA,   // [12][256][32] this layer (linear)
    const f16* __restrict__ wB,   // [4][256][32]  this layer (linear)
    const float* __restrict__ cb, // conv_b [256]
    const float* __restrict__ ob, // out_b  [128]
    int d)
{
    __shared__ __align__(16) f16 zs[64 * 136];   // 17408 B

    const int tid  = threadIdx.x;
    const int lane = tid & 63;
    const int w4   = tid >> 6;
    const int mg   = w4 & 1;
    const int ng   = w4 >> 1;
    const int col  = lane & 15;
    const int quad = lane >> 4;
    const int b    = blockIdx.y;
    const int t0   = blockIdx.x * 64;

    const f16* hb = h_in + (size_t)b * T_LEN * 128;

    // wave-invariant B base: this lane reads row (nb+col), k-group quad.
    // nt<4 -> +nt*512 ; nt>=4 -> +4096+(nt-4)*512 ; chunk ch -> +ch*8192.
    const f16* wAb = wA + (size_t)(ng * 64 + col) * 32 + quad * 8;
    const f16* wBb = wB + (size_t)(ng * 64 + col) * 32 + quad * 8;

    f32x4 acc[2][8];
#pragma unroll
    for (int mt = 0; mt < 2; ++mt)
#pragma unroll
        for (int nt = 0; nt < 8; ++nt) acc[mt][nt] = (f32x4)0.0f;

    // ---------------- Phase 1: pre = h * WA, K=384 (3 taps x 4 chunks) ------
    // No LDS, no barriers: B-frags are 16B dwordx4 loads from L2.
#pragma unroll
    for (int tap = 0; tap < 3; ++tap) {
        const int off = (2 - tap) * d;
        // hoisted A-load: full 2-row x 128-ch block for this tap
        f16x8 a[2][4];
#pragma unroll
        for (int mt = 0; mt < 2; ++mt) {
            int t = t0 + mg * 32 + mt * 16 + col - off;
            if (t >= 0) {
                const f16* hp = &hb[(size_t)t * 128 + quad * 8];
#pragma unroll
                for (int c = 0; c < 4; ++c) a[mt][c] = *(const f16x8*)&hp[c * 32];
            } else {
#pragma unroll
                for (int c = 0; c < 4; ++c) a[mt][c] = (f16x8)(f16)0.0f;
            }
        }
#pragma unroll
        for (int c = 0; c < 4; ++c) {
            const f16* bp = wAb + (tap * 4 + c) * 8192;
#pragma unroll
            for (int nt = 0; nt < 8; ++nt) {
                f16x8 bf = *(const f16x8*)&bp[(nt & 3) * 512 + (nt >> 2) * 4096];
                acc[0][nt] = MFMA_F16(a[0][c], bf, acc[0][nt], 0, 0, 0);
                acc[1][nt] = MFMA_F16(a[1][c], bf, acc[1][nt], 0, 0, 0);
            }
        }
    }

    // ---------------- Gating -> zs[64][136] ---------------------------------
#pragma unroll
    for (int nt = 0; nt < 4; ++nt) {
        int j = ng * 64 + nt * 16 + col;
        float cf = cb[j];
        float cg = cb[j + 128];
#pragma unroll
        for (int mt = 0; mt < 2; ++mt)
#pragma unroll
            for (int reg = 0; reg < 4; ++reg) {
                float f = acc[mt][nt][reg]     + cf;
                float g = acc[mt][nt + 4][reg] + cg;
                zs[(mg * 32 + mt * 16 + quad * 4 + reg) * 136 + j] =
                    (f16)(fast_tanh(f) * fast_sigmoid(g));
            }
    }
    __syncthreads();

    // ---------------- Phase 2: [res|skip] = z * WB, K=128; B from L2 --------
#pragma unroll
    for (int mt = 0; mt < 2; ++mt)
#pragma unroll
        for (int nt = 0; nt < 8; ++nt) acc[mt][nt] = (f32x4)0.0f;

#pragma unroll
    for (int ch = 0; ch < 4; ++ch) {
        f16x8 a[2];
#pragma unroll
        for (int mt = 0; mt < 2; ++mt)
            a[mt] = *(const f16x8*)&zs[(mg * 32 + mt * 16 + col) * 136 + ch * 32 + quad * 8];
        const f16* bp = wBb + ch * 8192;
#pragma unroll
        for (int nt = 0; nt < 8; ++nt) {
            f16x8 bf = *(const f16x8*)&bp[(nt & 3) * 512 + (nt >> 2) * 4096];
            acc[0][nt] = MFMA_F16(a[0], bf, acc[0][nt], 0, 0, 0);
            acc[1][nt] = MFMA_F16(a[1], bf, acc[1][nt], 0, 0, 0);
        }
    }
    __syncthreads();   // zs reads drained before epilogue overwrite

    // ---------------- Epilogue 1: h_out = h_in + res + ob (zs xpose) --------
#pragma unroll
    for (int nt = 0; nt < 4; ++nt) {
        int n = ng * 64 + nt * 16 + col;
        float o = ob[n];
#pragma unroll
        for (int mt = 0; mt < 2; ++mt)
#pragma unroll
            for (int reg = 0; reg < 4; ++reg)
                zs[(mg * 32 + mt * 16 + quad * 4 + reg) * 136 + n] =
                    (f16)(acc[mt][nt][reg] + o);
    }
    __syncthreads();
    const int orow = tid >> 2, oseg = tid & 3;
    const size_t gb = (size_t)b * T_LEN * 128 + (size_t)(t0 + orow) * 128 + oseg * 32;
#pragma unroll
    for (int i = 0; i < 4; ++i) {
        f16x8 rv = *(const f16x8*)&zs[orow * 136 + oseg * 32 + i * 8];
        f16x8 hv = *(const f16x8*)&h_in[gb + i * 8];
        *(f16x8*)&h_out[gb + i * 8] = hv + rv;
    }
    __syncthreads();

    // ---------------- Epilogue 2: acc1 += skip (zs xpose) -------------------
#pragma unroll
    for (int nt = 0; nt < 4; ++nt) {
        int n = ng * 64 + nt * 16 + col;
#pragma unroll
        for (int mt = 0; mt < 2; ++mt)
#pragma unroll
            for (int reg = 0; reg < 4; ++reg)
                zs[(mg * 32 + mt * 16 + quad * 4 + reg) * 136 + n] =
                    (f16)acc[mt][nt + 4][reg];
    }
    __syncthreads();
#pragma unroll
    for (int i = 0; i < 4; ++i) {
        f16x8 sv2 = *(const f16x8*)&zs[orow * 136 + oseg * 32 + i * 8];
        f16x8 av  = *(const f16x8*)&acc1[gb + i * 8];
        *(f16x8*)&acc1[gb + i * 8] = av + sv2;
    }
}

// out[bt] = o2b + sum_r o2w[r] * tanh(acc1[bt][r] + o1b[r]); one wave per bt
__global__ __launch_bounds__(256) void final_kernel(
    const f16* __restrict__ acc1, const float* __restrict__ b1,
    const float* __restrict__ w2, const float* __restrict__ b2,
    float* __restrict__ out)
{
    int lane = threadIdx.x & 63;
    int w = threadIdx.x >> 6;
    int bt = blockIdx.x * 4 + w;
    float v0 = (float)acc1[(size_t)bt * 128 + lane];
    float v1 = (float)acc1[(size_t)bt * 128 + lane + 64];
    float s = w2[lane] * fast_tanh(v0 + b1[lane]) +
              w2[lane + 64] * fast_tanh(v1 + b1[lane + 64]);
#pragma unroll
    for (int k = 1; k < 64; k <<= 1) s += __shfl_xor(s, k, 64);
    if (lane == 0) out[bt] = s + b2[0];
}

extern "C" void kernel_launch(void* const* d_in, const int* in_sizes, int n_in,
                              void* d_out, int out_size, void* d_ws, size_t ws_size,
                              hipStream_t stream)
{
    const float* x   = (const float*)d_in[0];
    const float* iw  = (const float*)d_in[1];
    const float* ib  = (const float*)d_in[2];
    const float* cw  = (const float*)d_in[3];
    const float* cb  = (const float*)d_in[4];
    const float* ow  = (const float*)d_in[5];
    const float* ob  = (const float*)d_in[6];
    const float* o1w = (const float*)d_in[7];
    const float* o1b = (const float*)d_in[8];
    const float* o2w = (const float*)d_in[9];
    const float* o2b = (const float*)d_in[10];
    float* out = (float*)d_out;

    const size_t HTR = (size_t)BATCH * T_LEN * 128;   // 16777216
    f16* hA   = (f16*)d_ws;
    f16* hB   = hA + HTR;
    f16* acc1 = hB + HTR;
    f16* wAp  = acc1 + HTR;
    f16* wBp  = wAp + (size_t)NLAYER * 12 * 256 * 32;
    // total ~ 3*32 MB + 2.4 MB = ~103 MB of ws

    prep_weights<<<4608, 256, 0, stream>>>(cw, ow, o1w, wAp, wBp);
    input_init<<<65536, 256, 0, stream>>>(x, iw, ib, hA, acc1);

    const int DIL[NLAYER] = {1, 2, 4, 8, 16, 32, 64, 128, 256};
    f16* hin = hA; f16* hout = hB;
    for (int l = 0; l < NLAYER; ++l) {
        layer_kernel<<<dim3(T_LEN / 64, BATCH), 256, 0, stream>>>(
            hin, hout, acc1,
            wAp + (size_t)l * 12 * 256 * 32, wBp + (size_t)l * 4 * 256 * 32,
            cb + l * 256, ob + l * 128, DIL[l]);
        f16* tmp = hin; hin = hout; hout = tmp;
    }
    final_kernel<<<BATCH * T_LEN / 4, 256, 0, stream>>>(acc1, o1b, o2w, o2b, out);
}

// Round 2
// 1014.823 us; speedup vs baseline: 4.2298x; 4.2298x over previous
//
#include <hip/hip_runtime.h>
#include <cstdint>
#include <cstddef>

#define T_LEN 16384
#define BATCH 8
#define NLAYER 9

typedef _Float16 f16;
typedef __attribute__((ext_vector_type(8))) _Float16 f16x8;
typedef __attribute__((ext_vector_type(4))) float f32x4;
#define MFMA_F16 __builtin_amdgcn_mfma_f32_16x16x32_f16

__device__ __forceinline__ float fast_sigmoid(float x) {
    return 1.0f / (1.0f + __expf(-x));
}
__device__ __forceinline__ float fast_tanh(float x) {
    return 1.0f - 2.0f / (__expf(2.0f * x) + 1.0f);
}

// ---------------------------------------------------------------------------
// Weight prepack to fp16, B-fragment order [n][k32-chunk], LINEAR layout.
//  Both wA and wB are read DIRECT from L2 by the layer kernel (weights are
//  192+64 KB per layer, shared by all 2048 blocks -> L2-resident). No LDS
//  staging => no swizzle needed.
// ---------------------------------------------------------------------------
__global__ __launch_bounds__(256) void prep_weights(
    const float* __restrict__ cw, const float* __restrict__ ow,
    const float* __restrict__ o1w, f16* __restrict__ wA, f16* __restrict__ wB)
{
    int n = blockIdx.x * 256 + threadIdx.x;
    const int NA = NLAYER * 12 * 256 * 32;   // 884736
    const int NB = NLAYER * 4 * 256 * 32;    // 294912
    if (n < NA) {
        int kp = n & 31; int q = n >> 5;
        int c = q & 255; q >>= 8;
        int ch = q % 12; int l = q / 12;
        int tap = ch >> 2;
        int r = (ch & 3) * 32 + kp;
        wA[n] = (f16)cw[((size_t)(l * 256 + c) * 128 + r) * 3 + tap];
    } else if (n < NA + NB) {
        int m = n - NA;
        int kp = m & 31; int q = m >> 5;
        int c = q & 255; q >>= 8;
        int ch = q & 3; int l = q >> 2;
        int k = ch * 32 + kp;
        float v = (c < 128) ? ow[(size_t)(l * 128 + c) * 128 + k]
                            : o1w[(size_t)(c - 128) * 1152 + l * 128 + k];
        wB[m] = (f16)v;
    }
}

// h[b][t][r] = tanh(iw[r]*x[b][t] + ib[r]) (fp16);  acc1 zero-init (fp16)
__global__ __launch_bounds__(256) void input_init(
    const float* __restrict__ x, const float* __restrict__ iw,
    const float* __restrict__ ib,
    f16* __restrict__ h, f16* __restrict__ acc1)
{
    int n = blockIdx.x * 256 + threadIdx.x;
    int r = n & 127; int bt = n >> 7;
    h[n] = (f16)fast_tanh(iw[r] * x[bt] + ib[r]);
    acc1[n] = (f16)0.0f;
}

// ---------------------------------------------------------------------------
// One layer. Block 256 thr = 4 waves (mg = w&1 splits M, ng = w>>1 splits N).
// Block tile M=64 x N=256; wave tile M=32 x N=128 (gate-paired filters).
// Phase 1 AND phase 2 read B direct from L2 (weights are L2-resident); no
//   phase-1 barriers; LDS = zs only (17.4 KB).
// launch_bounds(256,4): 128 regs/wave — fits acc (64 AGPR) + a-frags (32
//   VGPR) + b-frags/addressing, same profile round-0 compiled to (64+64, no
//   spill). DO NOT raise the min-waves arg: (256,8) capped regs at 64 and
//   spilled the accumulators to scratch (2 GB/dispatch scratch traffic,
//   MfmaUtil 2.8%, 6x regression — round-1 post-mortem).
// ---------------------------------------------------------------------------
__global__ __launch_bounds__(256, 4) void layer_kernel(
    const f16* __restrict__ h_in, f16* __restrict__ h_out,
    f16* __restrict__ acc1,
    const f16* __restrict__ wA,   // [12][256][32] this layer (linear)
    const f16* __restrict__ wB,   // [4][256][32]  this layer (linear)
    const float* __restrict__ cb, // conv_b [256]
    const float* __restrict__ ob, // out_b  [128]
    int d)
{
    __shared__ __align__(16) f16 zs[64 * 136];   // 17408 B

    const int tid  = threadIdx.x;
    const int lane = tid & 63;
    const int w4   = tid >> 6;
    const int mg   = w4 & 1;
    const int ng   = w4 >> 1;
    const int col  = lane & 15;
    const int quad = lane >> 4;
    const int b    = blockIdx.y;
    const int t0   = blockIdx.x * 64;

    const f16* hb = h_in + (size_t)b * T_LEN * 128;

    // wave-invariant B base: this lane reads row (nb+col), k-group quad.
    // nt<4 -> +nt*512 ; nt>=4 -> +4096+(nt-4)*512 ; chunk ch -> +ch*8192.
    const f16* wAb = wA + (size_t)(ng * 64 + col) * 32 + quad * 8;
    const f16* wBb = wB + (size_t)(ng * 64 + col) * 32 + quad * 8;

    f32x4 acc[2][8];
#pragma unroll
    for (int mt = 0; mt < 2; ++mt)
#pragma unroll
        for (int nt = 0; nt < 8; ++nt) acc[mt][nt] = (f32x4)0.0f;

    // ---------------- Phase 1: pre = h * WA, K=384 (3 taps x 4 chunks) ------
    // No LDS, no barriers: B-frags are 16B dwordx4 loads from L2.
#pragma unroll
    for (int tap = 0; tap < 3; ++tap) {
        const int off = (2 - tap) * d;
        // hoisted A-load: full 2-row x 128-ch block for this tap
        f16x8 a[2][4];
#pragma unroll
        for (int mt = 0; mt < 2; ++mt) {
            int t = t0 + mg * 32 + mt * 16 + col - off;
            if (t >= 0) {
                const f16* hp = &hb[(size_t)t * 128 + quad * 8];
#pragma unroll
                for (int c = 0; c < 4; ++c) a[mt][c] = *(const f16x8*)&hp[c * 32];
            } else {
#pragma unroll
                for (int c = 0; c < 4; ++c) a[mt][c] = (f16x8)(f16)0.0f;
            }
        }
#pragma unroll
        for (int c = 0; c < 4; ++c) {
            const f16* bp = wAb + (tap * 4 + c) * 8192;
#pragma unroll
            for (int nt = 0; nt < 8; ++nt) {
                f16x8 bf = *(const f16x8*)&bp[(nt & 3) * 512 + (nt >> 2) * 4096];
                acc[0][nt] = MFMA_F16(a[0][c], bf, acc[0][nt], 0, 0, 0);
                acc[1][nt] = MFMA_F16(a[1][c], bf, acc[1][nt], 0, 0, 0);
            }
        }
    }

    // ---------------- Gating -> zs[64][136] ---------------------------------
#pragma unroll
    for (int nt = 0; nt < 4; ++nt) {
        int j = ng * 64 + nt * 16 + col;
        float cf = cb[j];
        float cg = cb[j + 128];
#pragma unroll
        for (int mt = 0; mt < 2; ++mt)
#pragma unroll
            for (int reg = 0; reg < 4; ++reg) {
                float f = acc[mt][nt][reg]     + cf;
                float g = acc[mt][nt + 4][reg] + cg;
                zs[(mg * 32 + mt * 16 + quad * 4 + reg) * 136 + j] =
                    (f16)(fast_tanh(f) * fast_sigmoid(g));
            }
    }
    __syncthreads();

    // ---------------- Phase 2: [res|skip] = z * WB, K=128; B from L2 --------
#pragma unroll
    for (int mt = 0; mt < 2; ++mt)
#pragma unroll
        for (int nt = 0; nt < 8; ++nt) acc[mt][nt] = (f32x4)0.0f;

#pragma unroll
    for (int ch = 0; ch < 4; ++ch) {
        f16x8 a[2];
#pragma unroll
        for (int mt = 0; mt < 2; ++mt)
            a[mt] = *(const f16x8*)&zs[(mg * 32 + mt * 16 + col) * 136 + ch * 32 + quad * 8];
        const f16* bp = wBb + ch * 8192;
#pragma unroll
        for (int nt = 0; nt < 8; ++nt) {
            f16x8 bf = *(const f16x8*)&bp[(nt & 3) * 512 + (nt >> 2) * 4096];
            acc[0][nt] = MFMA_F16(a[0], bf, acc[0][nt], 0, 0, 0);
            acc[1][nt] = MFMA_F16(a[1], bf, acc[1][nt], 0, 0, 0);
        }
    }
    __syncthreads();   // zs reads drained before epilogue overwrite

    // ---------------- Epilogue 1: h_out = h_in + res + ob (zs xpose) --------
#pragma unroll
    for (int nt = 0; nt < 4; ++nt) {
        int n = ng * 64 + nt * 16 + col;
        float o = ob[n];
#pragma unroll
        for (int mt = 0; mt < 2; ++mt)
#pragma unroll
            for (int reg = 0; reg < 4; ++reg)
                zs[(mg * 32 + mt * 16 + quad * 4 + reg) * 136 + n] =
                    (f16)(acc[mt][nt][reg] + o);
    }
    __syncthreads();
    const int orow = tid >> 2, oseg = tid & 3;
    const size_t gb = (size_t)b * T_LEN * 128 + (size_t)(t0 + orow) * 128 + oseg * 32;
#pragma unroll
    for (int i = 0; i < 4; ++i) {
        f16x8 rv = *(const f16x8*)&zs[orow * 136 + oseg * 32 + i * 8];
        f16x8 hv = *(const f16x8*)&h_in[gb + i * 8];
        *(f16x8*)&h_out[gb + i * 8] = hv + rv;
    }
    __syncthreads();

    // ---------------- Epilogue 2: acc1 += skip (zs xpose) -------------------
#pragma unroll
    for (int nt = 0; nt < 4; ++nt) {
        int n = ng * 64 + nt * 16 + col;
#pragma unroll
        for (int mt = 0; mt < 2; ++mt)
#pragma unroll
            for (int reg = 0; reg < 4; ++reg)
                zs[(mg * 32 + mt * 16 + quad * 4 + reg) * 136 + n] =
                    (f16)acc[mt][nt + 4][reg];
    }
    __syncthreads();
#pragma unroll
    for (int i = 0; i < 4; ++i) {
        f16x8 sv2 = *(const f16x8*)&zs[orow * 136 + oseg * 32 + i * 8];
        f16x8 av  = *(const f16x8*)&acc1[gb + i * 8];
        *(f16x8*)&acc1[gb + i * 8] = av + sv2;
    }
}

// out[bt] = o2b + sum_r o2w[r] * tanh(acc1[bt][r] + o1b[r]); one wave per bt
__global__ __launch_bounds__(256) void final_kernel(
    const f16* __restrict__ acc1, const float* __restrict__ b1,
    const float* __restrict__ w2, const float* __restrict__ b2,
    float* __restrict__ out)
{
    int lane = threadIdx.x & 63;
    int w = threadIdx.x >> 6;
    int bt = blockIdx.x * 4 + w;
    float v0 = (float)acc1[(size_t)bt * 128 + lane];
    float v1 = (float)acc1[(size_t)bt * 128 + lane + 64];
    float s = w2[lane] * fast_tanh(v0 + b1[lane]) +
              w2[lane + 64] * fast_tanh(v1 + b1[lane + 64]);
#pragma unroll
    for (int k = 1; k < 64; k <<= 1) s += __shfl_xor(s, k, 64);
    if (lane == 0) out[bt] = s + b2[0];
}

extern "C" void kernel_launch(void* const* d_in, const int* in_sizes, int n_in,
                              void* d_out, int out_size, void* d_ws, size_t ws_size,
                              hipStream_t stream)
{
    const float* x   = (const float*)d_in[0];
    const float* iw  = (const float*)d_in[1];
    const float* ib  = (const float*)d_in[2];
    const float* cw  = (const float*)d_in[3];
    const float* cb  = (const float*)d_in[4];
    const float* ow  = (const float*)d_in[5];
    const float* ob  = (const float*)d_in[6];
    const float* o1w = (const float*)d_in[7];
    const float* o1b = (const float*)d_in[8];
    const float* o2w = (const float*)d_in[9];
    const float* o2b = (const float*)d_in[10];
    float* out = (float*)d_out;

    const size_t HTR = (size_t)BATCH * T_LEN * 128;   // 16777216
    f16* hA   = (f16*)d_ws;
    f16* hB   = hA + HTR;
    f16* acc1 = hB + HTR;
    f16* wAp  = acc1 + HTR;
    f16* wBp  = wAp + (size_t)NLAYER * 12 * 256 * 32;
    // total ~ 3*32 MB + 2.4 MB = ~103 MB of ws

    prep_weights<<<4608, 256, 0, stream>>>(cw, ow, o1w, wAp, wBp);
    input_init<<<65536, 256, 0, stream>>>(x, iw, ib, hA, acc1);

    const int DIL[NLAYER] = {1, 2, 4, 8, 16, 32, 64, 128, 256};
    f16* hin = hA; f16* hout = hB;
    for (int l = 0; l < NLAYER; ++l) {
        layer_kernel<<<dim3(T_LEN / 64, BATCH), 256, 0, stream>>>(
            hin, hout, acc1,
            wAp + (size_t)l * 12 * 256 * 32, wBp + (size_t)l * 4 * 256 * 32,
            cb + l * 256, ob + l * 128, DIL[l]);
        f16* tmp = hin; hin = hout; hout = tmp;
    }
    final_kernel<<<BATCH * T_LEN / 4, 256, 0, stream>>>(acc1, o1b, o2w, o2b, out);
}

// Round 3
// 812.749 us; speedup vs baseline: 5.2814x; 1.2486x over previous
//
#include <hip/hip_runtime.h>
#include <cstdint>
#include <cstddef>

#define T_LEN 16384
#define BATCH 8
#define NLAYER 9

typedef _Float16 f16;
typedef __attribute__((ext_vector_type(8))) _Float16 f16x8;
typedef __attribute__((ext_vector_type(4))) float f32x4;
#define MFMA_F16 __builtin_amdgcn_mfma_f32_16x16x32_f16

__device__ __forceinline__ float fast_sigmoid(float x) {
    return 1.0f / (1.0f + __expf(-x));
}
__device__ __forceinline__ float fast_tanh(float x) {
    return 1.0f - 2.0f / (__expf(2.0f * x) + 1.0f);
}

// async global->LDS DMA, 16 B per lane (dst = wave-uniform base + lane*16)
__device__ __forceinline__ void stage16(const f16* g, f16* l) {
    __builtin_amdgcn_global_load_lds(
        (const __attribute__((address_space(1))) unsigned int*)g,
        (__attribute__((address_space(3))) unsigned int*)l, 16, 0, 0);
}

// ---------------------------------------------------------------------------
// Weight prepack to fp16, B-fragment order [n][k32-chunk].
//  wA is stored PRE-SWIZZLED: within row n, 8-element group at slot i holds
//  logical group i ^ ((n>>1)&3). The layer kernel's linear global_load_lds
//  copy then reproduces the swizzled LDS image that the bswz frag-reads use.
//  wB stays linear (phase 2 reads direct from L2).
// ---------------------------------------------------------------------------
__global__ __launch_bounds__(256) void prep_weights(
    const float* __restrict__ cw, const float* __restrict__ ow,
    const float* __restrict__ o1w, f16* __restrict__ wA, f16* __restrict__ wB)
{
    int n = blockIdx.x * 256 + threadIdx.x;
    const int NA = NLAYER * 12 * 256 * 32;   // 884736
    const int NB = NLAYER * 4 * 256 * 32;    // 294912
    if (n < NA) {
        int kp = n & 31; int q = n >> 5;
        int c = q & 255; q >>= 8;
        int ch = q % 12; int l = q / 12;
        // n is the swizzled DESTINATION slot: map back to logical k
        int i = kp >> 3, j = kp & 7;
        int il = i ^ ((c >> 1) & 3);
        int kpl = il * 8 + j;
        int tap = ch >> 2;
        int r = (ch & 3) * 32 + kpl;
        wA[n] = (f16)cw[((size_t)(l * 256 + c) * 128 + r) * 3 + tap];
    } else if (n < NA + NB) {
        int m = n - NA;
        int kp = m & 31; int q = m >> 5;
        int c = q & 255; q >>= 8;
        int ch = q & 3; int l = q >> 2;
        int k = ch * 32 + kp;
        float v = (c < 128) ? ow[(size_t)(l * 128 + c) * 128 + k]
                            : o1w[(size_t)(c - 128) * 1152 + l * 128 + k];
        wB[m] = (f16)v;
    }
}

// h[b][t][r] = tanh(iw[r]*x[b][t] + ib[r]) (fp16);  acc1 zero-init (fp16)
__global__ __launch_bounds__(256) void input_init(
    const float* __restrict__ x, const float* __restrict__ iw,
    const float* __restrict__ ib,
    f16* __restrict__ h, f16* __restrict__ acc1)
{
    int n = blockIdx.x * 256 + threadIdx.x;
    int r = n & 127; int bt = n >> 7;
    h[n] = (f16)fast_tanh(iw[r] * x[bt] + ib[r]);
    acc1[n] = (f16)0.0f;
}

// ---------------------------------------------------------------------------
// One layer. Block 256 thr = 4 waves (mg = w&1 splits M, ng = w>>1 splits N).
// Block tile M=64 x N=256; wave tile M=32 x N=128 (gate-paired filters).
//
// Phase 1: B staged via global_load_lds (LDS reuse beats direct-L2: round-2
//   measured 786 MB/layer of L2 B-traffic = +24 µs/layer when read direct).
//   Barrier era uses COUNTED-STYLE wait: inline `s_waitcnt vmcnt(0)` + raw
//   s_barrier, with DMA(ch+1) issued AFTER the barrier — so the wait targets
//   a chunk issued one full iteration ago (covered by 16 MFMA + ds_reads),
//   not the just-issued prefetch. __syncthreads here would re-drain the
//   in-flight prefetch every chunk (round-0's ~500 cyc/chunk stall).
//   Invariants: (a) own vmcnt(0) before barrier => own DMA(ch) landed;
//   (b) reaching barrier => own prev-iter ds_reads retired (consumed by
//   MFMA) => post-barrier DMA into other buffer is race-free.
// Phase 2: B direct from L2 (wB 64 KB/layer, modest traffic); zs overlays
//   Bsm -> LDS 32 KB.
// XCD swizzle: xt=(bx&7)*32+(bx>>3) gives each XCD a contiguous 2048-row
//   t-slice per batch (~4-5 MB working set ~ per-XCD L2), and the mapping is
//   identical across the 9 layer launches => h_out written by XCD c is
//   re-read from c's L2 next layer.
// launch_bounds(256,4): 128 regs/wave. DO NOT raise: (256,8) capped regs at
//   64 and spilled the accumulators (2 GB/dispatch scratch, 6x regression —
//   round-1 post-mortem).
// ---------------------------------------------------------------------------
__global__ __launch_bounds__(256, 4) void layer_kernel(
    const f16* __restrict__ h_in, f16* __restrict__ h_out,
    f16* __restrict__ acc1,
    const f16* __restrict__ wA,   // [12][256][32] this layer (pre-swizzled)
    const f16* __restrict__ wB,   // [4][256][32]  this layer (linear)
    const float* __restrict__ cb, // conv_b [256]
    const float* __restrict__ ob, // out_b  [128]
    int d)
{
    __shared__ __align__(16) char smem_raw[32768];
    f16* const Bsm = (f16*)smem_raw;          // phase 1: [2][8192] (32 KB)
    f16* const zs  = (f16*)smem_raw;          // phase 2: [64][136] (17.4 KB)

    const int tid  = threadIdx.x;
    const int lane = tid & 63;
    const int w4   = tid >> 6;
    const int mg   = w4 & 1;
    const int ng   = w4 >> 1;
    const int col  = lane & 15;
    const int quad = lane >> 4;
    const int b    = blockIdx.y;
    // XCD-chunked tile swizzle: XCD = bx%8 gets contiguous xt in [c*32,(c+1)*32)
    const int bx   = blockIdx.x;
    const int xt   = ((bx & 7) << 5) | (bx >> 3);
    const int t0   = xt * 64;

    const f16* hb = h_in + (size_t)b * T_LEN * 128;

    const int bswz = (quad ^ ((col >> 1) & 3)) * 8;  // swizzled chunk offset (reads)

    f32x4 acc[2][8];
#pragma unroll
    for (int mt = 0; mt < 2; ++mt)
#pragma unroll
        for (int nt = 0; nt < 8; ++nt) acc[mt][nt] = (f32x4)0.0f;

    // ---------------- Phase 1: pre = h * WA, K=384 (3 taps x 4 chunks) ------
    {   // prologue: DMA chunk 0 -> buf 0 (linear copy; image already swizzled)
        const f16* src = wA + w4 * 2048 + lane * 8;
        f16* dst = Bsm + w4 * 2048;
#pragma unroll
        for (int i = 0; i < 4; ++i) stage16(src + i * 512, dst + i * 512);
    }

#pragma unroll
    for (int tap = 0; tap < 3; ++tap) {
        const int off = (2 - tap) * d;
        f16x8 a[2][4];
#pragma unroll
        for (int c = 0; c < 4; ++c) {
            const int ch = tap * 4 + c;
            // ---- counted-wait barrier era (no drain of in-flight prefetch)
            __builtin_amdgcn_sched_barrier(0);
            asm volatile("s_waitcnt vmcnt(0)" ::: "memory");
            __builtin_amdgcn_s_barrier();
            __builtin_amdgcn_sched_barrier(0);
            if (ch < 11) {   // prefetch next chunk into the other buffer
                const f16* src = wA + (ch + 1) * 8192 + w4 * 2048 + lane * 8;
                f16* dst = Bsm + ((ch + 1) & 1) * 8192 + w4 * 2048;
#pragma unroll
                for (int i = 0; i < 4; ++i) stage16(src + i * 512, dst + i * 512);
            }
            if (c == 0) {    // hoisted A-load: 2-row x 128-ch block, this tap
#pragma unroll
                for (int mt = 0; mt < 2; ++mt) {
                    int t = t0 + mg * 32 + mt * 16 + col - off;
                    if (t >= 0) {
                        const f16* hp = &hb[(size_t)t * 128 + quad * 8];
#pragma unroll
                        for (int cc = 0; cc < 4; ++cc)
                            a[mt][cc] = *(const f16x8*)&hp[cc * 32];
                    } else {
#pragma unroll
                        for (int cc = 0; cc < 4; ++cc)
                            a[mt][cc] = (f16x8)(f16)0.0f;
                    }
                }
            }
            const f16* bsc = Bsm + (ch & 1) * 8192;
#pragma unroll
            for (int nt = 0; nt < 8; ++nt) {
                int nb = (nt < 4) ? (ng * 64 + nt * 16)
                                  : (128 + ng * 64 + (nt - 4) * 16);
                f16x8 bf = *(const f16x8*)&bsc[(nb + col) * 32 + bswz];
                acc[0][nt] = MFMA_F16(a[0][c], bf, acc[0][nt], 0, 0, 0);
                acc[1][nt] = MFMA_F16(a[1][c], bf, acc[1][nt], 0, 0, 0);
            }
        }
    }
    __syncthreads();   // full drain before zs overlays Bsm

    // ---------------- Gating -> zs[64][136] (overlays Bsm) ------------------
#pragma unroll
    for (int nt = 0; nt < 4; ++nt) {
        int j = ng * 64 + nt * 16 + col;
        float cf = cb[j];
        float cg = cb[j + 128];
#pragma unroll
        for (int mt = 0; mt < 2; ++mt)
#pragma unroll
            for (int reg = 0; reg < 4; ++reg) {
                float f = acc[mt][nt][reg]     + cf;
                float g = acc[mt][nt + 4][reg] + cg;
                zs[(mg * 32 + mt * 16 + quad * 4 + reg) * 136 + j] =
                    (f16)(fast_tanh(f) * fast_sigmoid(g));
            }
    }
    __syncthreads();

    // ---------------- Phase 2: [res|skip] = z * WB, K=128; B from L2 --------
#pragma unroll
    for (int mt = 0; mt < 2; ++mt)
#pragma unroll
        for (int nt = 0; nt < 8; ++nt) acc[mt][nt] = (f32x4)0.0f;

#pragma unroll
    for (int ch = 0; ch < 4; ++ch) {
        f16x8 a[2];
#pragma unroll
        for (int mt = 0; mt < 2; ++mt)
            a[mt] = *(const f16x8*)&zs[(mg * 32 + mt * 16 + col) * 136 + ch * 32 + quad * 8];
        const f16* wc = wB + ch * 8192;
#pragma unroll
        for (int nt = 0; nt < 8; ++nt) {
            int nb = (nt < 4) ? (ng * 64 + nt * 16)
                              : (128 + ng * 64 + (nt - 4) * 16);
            f16x8 bf = *(const f16x8*)&wc[(nb + col) * 32 + quad * 8];
            acc[0][nt] = MFMA_F16(a[0], bf, acc[0][nt], 0, 0, 0);
            acc[1][nt] = MFMA_F16(a[1], bf, acc[1][nt], 0, 0, 0);
        }
    }
    __syncthreads();   // zs reads drained before epilogue overwrite

    // ---------------- Epilogue 1: h_out = h_in + res + ob (zs xpose) --------
#pragma unroll
    for (int nt = 0; nt < 4; ++nt) {
        int n = ng * 64 + nt * 16 + col;
        float o = ob[n];
#pragma unroll
        for (int mt = 0; mt < 2; ++mt)
#pragma unroll
            for (int reg = 0; reg < 4; ++reg)
                zs[(mg * 32 + mt * 16 + quad * 4 + reg) * 136 + n] =
                    (f16)(acc[mt][nt][reg] + o);
    }
    __syncthreads();
    const int orow = tid >> 2, oseg = tid & 3;
    const size_t gb = (size_t)b * T_LEN * 128 + (size_t)(t0 + orow) * 128 + oseg * 32;
#pragma unroll
    for (int i = 0; i < 4; ++i) {
        f16x8 rv = *(const f16x8*)&zs[orow * 136 + oseg * 32 + i * 8];
        f16x8 hv = *(const f16x8*)&h_in[gb + i * 8];
        *(f16x8*)&h_out[gb + i * 8] = hv + rv;
    }
    __syncthreads();

    // ---------------- Epilogue 2: acc1 += skip (zs xpose) -------------------
#pragma unroll
    for (int nt = 0; nt < 4; ++nt) {
        int n = ng * 64 + nt * 16 + col;
#pragma unroll
        for (int mt = 0; mt < 2; ++mt)
#pragma unroll
            for (int reg = 0; reg < 4; ++reg)
                zs[(mg * 32 + mt * 16 + quad * 4 + reg) * 136 + n] =
                    (f16)acc[mt][nt + 4][reg];
    }
    __syncthreads();
#pragma unroll
    for (int i = 0; i < 4; ++i) {
        f16x8 sv2 = *(const f16x8*)&zs[orow * 136 + oseg * 32 + i * 8];
        f16x8 av  = *(const f16x8*)&acc1[gb + i * 8];
        *(f16x8*)&acc1[gb + i * 8] = av + sv2;
    }
}

// out[bt] = o2b + sum_r o2w[r] * tanh(acc1[bt][r] + o1b[r]); one wave per bt
__global__ __launch_bounds__(256) void final_kernel(
    const f16* __restrict__ acc1, const float* __restrict__ b1,
    const float* __restrict__ w2, const float* __restrict__ b2,
    float* __restrict__ out)
{
    int lane = threadIdx.x & 63;
    int w = threadIdx.x >> 6;
    int bt = blockIdx.x * 4 + w;
    float v0 = (float)acc1[(size_t)bt * 128 + lane];
    float v1 = (float)acc1[(size_t)bt * 128 + lane + 64];
    float s = w2[lane] * fast_tanh(v0 + b1[lane]) +
              w2[lane + 64] * fast_tanh(v1 + b1[lane + 64]);
#pragma unroll
    for (int k = 1; k < 64; k <<= 1) s += __shfl_xor(s, k, 64);
    if (lane == 0) out[bt] = s + b2[0];
}

extern "C" void kernel_launch(void* const* d_in, const int* in_sizes, int n_in,
                              void* d_out, int out_size, void* d_ws, size_t ws_size,
                              hipStream_t stream)
{
    const float* x   = (const float*)d_in[0];
    const float* iw  = (const float*)d_in[1];
    const float* ib  = (const float*)d_in[2];
    const float* cw  = (const float*)d_in[3];
    const float* cb  = (const float*)d_in[4];
    const float* ow  = (const float*)d_in[5];
    const float* ob  = (const float*)d_in[6];
    const float* o1w = (const float*)d_in[7];
    const float* o1b = (const float*)d_in[8];
    const float* o2w = (const float*)d_in[9];
    const float* o2b = (const float*)d_in[10];
    float* out = (float*)d_out;

    const size_t HTR = (size_t)BATCH * T_LEN * 128;   // 16777216
    f16* hA   = (f16*)d_ws;
    f16* hB   = hA + HTR;
    f16* acc1 = hB + HTR;
    f16* wAp  = acc1 + HTR;
    f16* wBp  = wAp + (size_t)NLAYER * 12 * 256 * 32;
    // total ~ 3*32 MB + 2.4 MB = ~103 MB of ws

    prep_weights<<<4608, 256, 0, stream>>>(cw, ow, o1w, wAp, wBp);
    input_init<<<65536, 256, 0, stream>>>(x, iw, ib, hA, acc1);

    const int DIL[NLAYER] = {1, 2, 4, 8, 16, 32, 64, 128, 256};
    f16* hin = hA; f16* hout = hB;
    for (int l = 0; l < NLAYER; ++l) {
        layer_kernel<<<dim3(T_LEN / 64, BATCH), 256, 0, stream>>>(
            hin, hout, acc1,
            wAp + (size_t)l * 12 * 256 * 32, wBp + (size_t)l * 4 * 256 * 32,
            cb + l * 256, ob + l * 128, DIL[l]);
        f16* tmp = hin; hin = hout; hout = tmp;
    }
    final_kernel<<<BATCH * T_LEN / 4, 256, 0, stream>>>(acc1, o1b, o2w, o2b, out);
}

// Round 4
// 754.829 us; speedup vs baseline: 5.6867x; 1.0767x over previous
//
#include <hip/hip_runtime.h>
#include <cstdint>
#include <cstddef>

#define T_LEN 16384
#define BATCH 8
#define NLAYER 9

typedef _Float16 f16;
typedef __attribute__((ext_vector_type(8))) _Float16 f16x8;
typedef __attribute__((ext_vector_type(4))) float f32x4;
#define MFMA_F16 __builtin_amdgcn_mfma_f32_16x16x32_f16

// async global->LDS DMA, 16 B per lane (dst = wave-uniform base + lane*16)
__device__ __forceinline__ void stage16(const f16* g, f16* l) {
    __builtin_amdgcn_global_load_lds(
        (const __attribute__((address_space(1))) unsigned int*)g,
        (__attribute__((address_space(3))) unsigned int*)l, 16, 0, 0);
}

__device__ __forceinline__ float fast_tanh(float x) {
    return 1.0f - 2.0f / (__expf(2.0f * x) + 1.0f);
}

// ---------------------------------------------------------------------------
// Weight prepack to fp16, B-fragment order [n][k32-chunk].
//  wA pre-swizzled per row (slot i holds logical group i ^ ((n>>1)&3)) so the
//  layer kernel's LINEAR global_load_lds copy reproduces the swizzled LDS
//  image the bswz frag-reads expect. Swizzle is within-row => independent of
//  the half-chunk staging granularity. wB linear (phase 2 reads from L2).
// ---------------------------------------------------------------------------
__global__ __launch_bounds__(256) void prep_weights(
    const float* __restrict__ cw, const float* __restrict__ ow,
    const float* __restrict__ o1w, f16* __restrict__ wA, f16* __restrict__ wB)
{
    int n = blockIdx.x * 256 + threadIdx.x;
    const int NA = NLAYER * 12 * 256 * 32;   // 884736
    const int NB = NLAYER * 4 * 256 * 32;    // 294912
    if (n < NA) {
        int kp = n & 31; int q = n >> 5;
        int c = q & 255; q >>= 8;
        int ch = q % 12; int l = q / 12;
        int i = kp >> 3, j = kp & 7;
        int il = i ^ ((c >> 1) & 3);
        int kpl = il * 8 + j;
        int tap = ch >> 2;
        int r = (ch & 3) * 32 + kpl;
        wA[n] = (f16)cw[((size_t)(l * 256 + c) * 128 + r) * 3 + tap];
    } else if (n < NA + NB) {
        int m = n - NA;
        int kp = m & 31; int q = m >> 5;
        int c = q & 255; q >>= 8;
        int ch = q & 3; int l = q >> 2;
        int k = ch * 32 + kp;
        float v = (c < 128) ? ow[(size_t)(l * 128 + c) * 128 + k]
                            : o1w[(size_t)(c - 128) * 1152 + l * 128 + k];
        wB[m] = (f16)v;
    }
}

// h[b][t][r] = tanh(iw[r]*x[b][t] + ib[r]) (fp16);  acc1 zero-init (fp16)
__global__ __launch_bounds__(256) void input_init(
    const float* __restrict__ x, const float* __restrict__ iw,
    const float* __restrict__ ib,
    f16* __restrict__ h, f16* __restrict__ acc1)
{
    int n = blockIdx.x * 256 + threadIdx.x;
    int r = n & 127; int bt = n >> 7;
    h[n] = (f16)fast_tanh(iw[r] * x[bt] + ib[r]);
    acc1[n] = (f16)0.0f;
}

// ---------------------------------------------------------------------------
// One layer. 256 thr = 4 waves (mg = w&1 splits M, ng = w>>1 splits N).
// Block tile M=64 x N=256; wave tile M=32 x N=128 (gate-paired filters).
//
// Phase 1: depth-2 DMA pipeline. 24 half-chunk eras (8 KB each), 4 LDS bufs
//   (32 KB total). Era hc: issue DMA(hc+2); 4 ds_read + 8 MFMA on buf(hc);
//   `s_waitcnt vmcnt(2)` (keeps this era's 2 stage16 in flight) + raw
//   s_barrier. Each DMA gets ~2 eras of cover (rounds 0/3 were depth-1 and
//   identical => the ~1-era-covered wait was the measured stall).
//   A-loads are ALWAYS issued (clamped t + per-lane select) so the manual
//   vmcnt counts are exec-mask-independent.
// Gating: fused 3-trans form (2 exp2 + 1 rcp per z vs 4 trans).
// Phase 2: B direct from L2. Tail: res+skip written to zsR/zsS in one pass,
//   single barrier, 8 epilogue global loads issued together (RMW chains
//   overlap). LDS 34816 B -> still 4 blocks/CU.
// launch_bounds(256,4): 128 regs/wave. DO NOT raise: (256,8) spilled the
//   accumulators (round-1: 2 GB scratch, 6x regression).
// ---------------------------------------------------------------------------
__global__ __launch_bounds__(256, 4) void layer_kernel(
    const f16* __restrict__ h_in, f16* __restrict__ h_out,
    f16* __restrict__ acc1,
    const f16* __restrict__ wA,   // [12][256][32] this layer (pre-swizzled)
    const f16* __restrict__ wB,   // [4][256][32]  this layer (linear)
    const float* __restrict__ cb, // conv_b [256]
    const float* __restrict__ ob, // out_b  [128]
    int d)
{
    __shared__ __align__(16) char smem_raw[34816];
    f16* const Bsm = (f16*)smem_raw;            // phase 1: 4 bufs x 4096 f16
    f16* const zsR = (f16*)smem_raw;            // z, then res: [64][136]
    f16* const zsS = (f16*)smem_raw + 8704;     // skip:        [64][136]

    const int tid  = threadIdx.x;
    const int lane = tid & 63;
    const int w4   = tid >> 6;
    const int mg   = w4 & 1;
    const int ng   = w4 >> 1;
    const int col  = lane & 15;
    const int quad = lane >> 4;
    const int b    = blockIdx.y;
    const int bx   = blockIdx.x;
    const int xt   = ((bx & 7) << 5) | (bx >> 3);   // XCD-chunked swizzle
    const int t0   = xt * 64;

    const f16* hb = h_in + (size_t)b * T_LEN * 128;
    const int bswz = (quad ^ ((col >> 1) & 3)) * 8;

    f32x4 acc[2][8];
#pragma unroll
    for (int mt = 0; mt < 2; ++mt)
#pragma unroll
        for (int nt = 0; nt < 8; ++nt) acc[mt][nt] = (f32x4)0.0f;

    f16x8 a[2][4];
    // unconditional A-load (uniform vmem count) + per-lane zero select
    auto loadA = [&](int tap) {
        const int off = (2 - tap) * d;
#pragma unroll
        for (int mt = 0; mt < 2; ++mt) {
            int t = t0 + mg * 32 + mt * 16 + col - off;
            int tc = t < 0 ? 0 : t;
            const f16* hp = &hb[(size_t)tc * 128 + quad * 8];
#pragma unroll
            for (int cc = 0; cc < 4; ++cc) {
                f16x8 v = *(const f16x8*)&hp[cc * 32];
                a[mt][cc] = (t >= 0) ? v : (f16x8)(f16)0.0f;
            }
        }
    };

    // ---------------- Phase 1: pre = h * WA, K=384 (24 half-chunk eras) -----
    {   // prologue: DMA half-chunks 0,1 (bufs 0,1), A-loads tap0, wait DMA(0)
        const f16* s0 = wA + w4 * 1024 + lane * 8;
        f16* d0 = Bsm + w4 * 1024;
        stage16(s0, d0); stage16(s0 + 512, d0 + 512);
        const f16* s1 = wA + 4096 + w4 * 1024 + lane * 8;
        f16* d1 = Bsm + 4096 + w4 * 1024;
        stage16(s1, d1); stage16(s1 + 512, d1 + 512);
        __builtin_amdgcn_sched_barrier(0);
        loadA(0);                                     // 8 loads, always issued
        __builtin_amdgcn_sched_barrier(0);
        // outstanding = 2(DMA0)+2(DMA1)+8(A) = 12; wait oldest 2 = DMA(0)
        asm volatile("s_waitcnt vmcnt(10)" ::: "memory");
        __builtin_amdgcn_s_barrier();
        __builtin_amdgcn_sched_barrier(0);
    }

#pragma unroll
    for (int hc = 0; hc < 24; ++hc) {
        if (hc == 8) loadA(1);
        if (hc == 16) loadA(2);
        if (hc + 2 < 24) {   // issue DMA two eras ahead
            const f16* s = wA + (hc + 2) * 4096 + w4 * 1024 + lane * 8;
            f16* dd = Bsm + ((hc + 2) & 3) * 4096 + w4 * 1024;
            stage16(s, dd); stage16(s + 512, dd + 512);
        }
        const f16* bsc = Bsm + (hc & 3) * 4096;
        const int c = (hc >> 1) & 3;          // k-chunk within tap
        const int nbase = (hc & 1) * 4;       // row-half -> nt range
#pragma unroll
        for (int ntl = 0; ntl < 4; ++ntl) {
            int row = ng * 64 + ntl * 16 + col;   // local row within 128
            f16x8 bf = *(const f16x8*)&bsc[row * 32 + bswz];
            acc[0][nbase + ntl] = MFMA_F16(a[0][c], bf, acc[0][nbase + ntl], 0, 0, 0);
            acc[1][nbase + ntl] = MFMA_F16(a[1][c], bf, acc[1][nbase + ntl], 0, 0, 0);
        }
        __builtin_amdgcn_sched_barrier(0);
        if (hc == 22) {
            asm volatile("s_waitcnt vmcnt(0)" ::: "memory");   // drain DMA(23)
        } else if (hc < 22) {
            asm volatile("s_waitcnt vmcnt(2)" ::: "memory");   // DMA(hc+1) done
        }
        if (hc < 23) __builtin_amdgcn_s_barrier();
        __builtin_amdgcn_sched_barrier(0);
    }
    __syncthreads();   // all Bsm reads done before z overlays

    // ---------------- Gating -> zsR (3-trans fused tanh*sigmoid) ------------
#pragma unroll
    for (int nt = 0; nt < 4; ++nt) {
        int j = ng * 64 + nt * 16 + col;
        float cf = cb[j];
        float cg = cb[j + 128];
#pragma unroll
        for (int mt = 0; mt < 2; ++mt)
#pragma unroll
            for (int reg = 0; reg < 4; ++reg) {
                float f = acc[mt][nt][reg]     + cf;
                float g = acc[mt][nt + 4][reg] + cg;
                float E = __builtin_amdgcn_exp2f(2.885390082f * f); // e^(2f)
                float S = __builtin_amdgcn_exp2f(1.442695041f * g); // e^(g)
                float z = (E - 1.0f) * S *
                          __builtin_amdgcn_rcpf((E + 1.0f) * (S + 1.0f));
                zsR[(mg * 32 + mt * 16 + quad * 4 + reg) * 136 + j] = (f16)z;
            }
    }
    __syncthreads();

    // ---------------- Phase 2: [res|skip] = z * WB, K=128; B from L2 --------
#pragma unroll
    for (int mt = 0; mt < 2; ++mt)
#pragma unroll
        for (int nt = 0; nt < 8; ++nt) acc[mt][nt] = (f32x4)0.0f;

#pragma unroll
    for (int ch = 0; ch < 4; ++ch) {
        f16x8 a2[2];
#pragma unroll
        for (int mt = 0; mt < 2; ++mt)
            a2[mt] = *(const f16x8*)&zsR[(mg * 32 + mt * 16 + col) * 136 + ch * 32 + quad * 8];
        const f16* wc = wB + ch * 8192;
#pragma unroll
        for (int nt = 0; nt < 8; ++nt) {
            int nb = (nt < 4) ? (ng * 64 + nt * 16)
                              : (128 + ng * 64 + (nt - 4) * 16);
            f16x8 bf = *(const f16x8*)&wc[(nb + col) * 32 + quad * 8];
            acc[0][nt] = MFMA_F16(a2[0], bf, acc[0][nt], 0, 0, 0);
            acc[1][nt] = MFMA_F16(a2[1], bf, acc[1][nt], 0, 0, 0);
        }
    }
    __syncthreads();   // z reads drained before res overwrites zsR

    // ---------------- Merged epilogue: res->zsR, skip->zsS, one barrier -----
#pragma unroll
    for (int nt = 0; nt < 4; ++nt) {
        int n = ng * 64 + nt * 16 + col;
        float o = ob[n];
#pragma unroll
        for (int mt = 0; mt < 2; ++mt)
#pragma unroll
            for (int reg = 0; reg < 4; ++reg) {
                int r = (mg * 32 + mt * 16 + quad * 4 + reg) * 136 + n;
                zsR[r] = (f16)(acc[mt][nt][reg] + o);
                zsS[r] = (f16)acc[mt][nt + 4][reg];
            }
    }
    __syncthreads();
    const int orow = tid >> 2, oseg = tid & 3;
    const size_t gb = (size_t)b * T_LEN * 128 + (size_t)(t0 + orow) * 128 + oseg * 32;
    f16x8 hv[4], av[4];
#pragma unroll
    for (int i = 0; i < 4; ++i) hv[i] = *(const f16x8*)&h_in[gb + i * 8];
#pragma unroll
    for (int i = 0; i < 4; ++i) av[i] = *(const f16x8*)&acc1[gb + i * 8];
#pragma unroll
    for (int i = 0; i < 4; ++i) {
        f16x8 rv = *(const f16x8*)&zsR[orow * 136 + oseg * 32 + i * 8];
        *(f16x8*)&h_out[gb + i * 8] = hv[i] + rv;
    }
#pragma unroll
    for (int i = 0; i < 4; ++i) {
        f16x8 sv = *(const f16x8*)&zsS[orow * 136 + oseg * 32 + i * 8];
        *(f16x8*)&acc1[gb + i * 8] = av[i] + sv;
    }
}

// out[bt] = o2b + sum_r o2w[r] * tanh(acc1[bt][r] + o1b[r]); one wave per bt
__global__ __launch_bounds__(256) void final_kernel(
    const f16* __restrict__ acc1, const float* __restrict__ b1,
    const float* __restrict__ w2, const float* __restrict__ b2,
    float* __restrict__ out)
{
    int lane = threadIdx.x & 63;
    int w = threadIdx.x >> 6;
    int bt = blockIdx.x * 4 + w;
    float v0 = (float)acc1[(size_t)bt * 128 + lane];
    float v1 = (float)acc1[(size_t)bt * 128 + lane + 64];
    float s = w2[lane] * fast_tanh(v0 + b1[lane]) +
              w2[lane + 64] * fast_tanh(v1 + b1[lane + 64]);
#pragma unroll
    for (int k = 1; k < 64; k <<= 1) s += __shfl_xor(s, k, 64);
    if (lane == 0) out[bt] = s + b2[0];
}

extern "C" void kernel_launch(void* const* d_in, const int* in_sizes, int n_in,
                              void* d_out, int out_size, void* d_ws, size_t ws_size,
                              hipStream_t stream)
{
    const float* x   = (const float*)d_in[0];
    const float* iw  = (const float*)d_in[1];
    const float* ib  = (const float*)d_in[2];
    const float* cw  = (const float*)d_in[3];
    const float* cb  = (const float*)d_in[4];
    const float* ow  = (const float*)d_in[5];
    const float* ob  = (const float*)d_in[6];
    const float* o1w = (const float*)d_in[7];
    const float* o1b = (const float*)d_in[8];
    const float* o2w = (const float*)d_in[9];
    const float* o2b = (const float*)d_in[10];
    float* out = (float*)d_out;

    const size_t HTR = (size_t)BATCH * T_LEN * 128;   // 16777216
    f16* hA   = (f16*)d_ws;
    f16* hB   = hA + HTR;
    f16* acc1 = hB + HTR;
    f16* wAp  = acc1 + HTR;
    f16* wBp  = wAp + (size_t)NLAYER * 12 * 256 * 32;
    // total ~ 3*32 MB + 2.4 MB = ~103 MB of ws

    prep_weights<<<4608, 256, 0, stream>>>(cw, ow, o1w, wAp, wBp);
    input_init<<<65536, 256, 0, stream>>>(x, iw, ib, hA, acc1);

    const int DIL[NLAYER] = {1, 2, 4, 8, 16, 32, 64, 128, 256};
    f16* hin = hA; f16* hout = hB;
    for (int l = 0; l < NLAYER; ++l) {
        layer_kernel<<<dim3(T_LEN / 64, BATCH), 256, 0, stream>>>(
            hin, hout, acc1,
            wAp + (size_t)l * 12 * 256 * 32, wBp + (size_t)l * 4 * 256 * 32,
            cb + l * 256, ob + l * 128, DIL[l]);
        f16* tmp = hin; hin = hout; hout = tmp;
    }
    final_kernel<<<BATCH * T_LEN / 4, 256, 0, stream>>>(acc1, o1b, o2w, o2b, out);
}